// Round 1
// 462.140 us; speedup vs baseline: 1.0216x; 1.0216x over previous
//
#include <hip/hip_runtime.h>
#include <math.h>

typedef unsigned int u32;
typedef unsigned short u16;
using half8 = __attribute__((ext_vector_type(8))) _Float16;
using f32x4 = __attribute__((ext_vector_type(4))) float;

#define NN 20000
#define MPAD 20096          // 157 * 128
#define NE 160000
#define ET 180000           // NE + NN self loops
#define NG 64
#define NBLK 79             // ceil(NN/256)

constexpr float NEG_ATT = 0.2f;
constexpr float NEG_ACT = 0.01f;
constexpr float EPS_GN  = 1e-5f;

struct Ptr4 { const float *p0, *p1, *p2, *p3; };

// ---------- helpers ----------

__device__ __forceinline__ u16 f2h(float f) {
    _Float16 h = (_Float16)f;
    return __builtin_bit_cast(u16, h);
}
__device__ __forceinline__ float h2f(u16 b) {
    return (float)__builtin_bit_cast(_Float16, b);
}

__device__ __forceinline__ void gl_lds16(const void* g, void* l) {
    __builtin_amdgcn_global_load_lds((const __attribute__((address_space(1))) u32*)g,
                                     (__attribute__((address_space(3))) u32*)l, 16, 0, 0);
}

__device__ __forceinline__ u32 enc_f(float f) {        // orderable uint
    u32 b = __float_as_uint(f);
    return (b & 0x80000000u) ? ~b : (b | 0x80000000u);
}
__device__ __forceinline__ float dec_f(u32 u) {
    u32 b = (u & 0x80000000u) ? (u & 0x7fffffffu) : ~u;
    return __uint_as_float(b);
}
__device__ __forceinline__ float lrelu_att(float v) {
    return (v > 0.f) ? v : NEG_ATT * v;
}

// ---------------- graph bounds via binary search (batch is sorted) ----------------

__global__ void k_bounds(const int* __restrict__ batch, int* __restrict__ counts) {
    __shared__ int ls[NG + 1];
    int g = threadIdx.x;           // 64 threads
    int lo = 0, hi = NN;
    while (lo < hi) {
        int mid = (lo + hi) >> 1;
        if (batch[mid] < g) lo = mid + 1; else hi = mid;
    }
    ls[g] = lo;
    if (g == 0) ls[NG] = NN;
    __syncthreads();
    counts[g] = ls[g + 1] - ls[g];
}

// ---------------- CSR build ----------------

__global__ void k_deg(const int* __restrict__ ei, int* deg) {
    int i = blockIdx.x * 256 + threadIdx.x;
    if (i >= ET) return;
    int dst = (i < NE) ? ei[NE + i] : (i - NE);
    atomicAdd(&deg[dst], 1);
}

__global__ void k_scan1(const int* __restrict__ deg, int* __restrict__ bsum) {
    int i = blockIdx.x * 256 + threadIdx.x;
    int v = (i < NN) ? deg[i] : 0;
    int lane = threadIdx.x & 63, w = threadIdx.x >> 6;
    #pragma unroll
    for (int off = 32; off; off >>= 1) v += __shfl_down(v, off, 64);
    __shared__ int ws[4];
    if (lane == 0) ws[w] = v;
    __syncthreads();
    if (threadIdx.x == 0) bsum[blockIdx.x] = ws[0] + ws[1] + ws[2] + ws[3];
}

__global__ void k_scan2(const int* __restrict__ bsum, int* __restrict__ boff,
                        int* __restrict__ total) {
    int tid = threadIdx.x;      // 256
    int v = (tid < NBLK) ? bsum[tid] : 0;
    int lane = tid & 63, w = tid >> 6;
    int val = v;
    #pragma unroll
    for (int off = 1; off < 64; off <<= 1) {
        int t = __shfl_up(val, off, 64);
        if (lane >= off) val += t;
    }
    __shared__ int ws[4];
    if (lane == 63) ws[w] = val;
    __syncthreads();
    int woff = 0;
    for (int k = 0; k < w; k++) woff += ws[k];
    int excl = woff + val - v;
    if (tid < NBLK) boff[tid] = excl;
    if (tid == NBLK - 1) *total = excl + v;
}

__global__ void k_scan3(const int* __restrict__ deg, const int* __restrict__ boff,
                        int* __restrict__ row_ptr, int* __restrict__ cursor) {
    int i = blockIdx.x * 256 + threadIdx.x;
    int v = (i < NN) ? deg[i] : 0;
    int lane = threadIdx.x & 63, w = threadIdx.x >> 6;
    int val = v;
    #pragma unroll
    for (int off = 1; off < 64; off <<= 1) {
        int t = __shfl_up(val, off, 64);
        if (lane >= off) val += t;
    }
    __shared__ int ws[4];
    if (lane == 63) ws[w] = val;
    __syncthreads();
    int woff = 0;
    for (int k = 0; k < w; k++) woff += ws[k];
    int excl = boff[blockIdx.x] + woff + val - v;
    if (i < NN) { row_ptr[i] = excl; cursor[i] = excl; }
}

__global__ void k_scatter(const int* __restrict__ ei, int* cursor, int* __restrict__ col) {
    int i = blockIdx.x * 256 + threadIdx.x;
    if (i >= ET) return;
    int s, d;
    if (i < NE) { s = ei[i]; d = ei[NE + i]; } else { s = i - NE; d = s; }
    int p = atomicAdd(&cursor[d], 1);
    col[p] = s;
}

// ---------------- all-layer wsrc = W @ asrc, wdst = W @ adst ----------------

__global__ void k_wvec_all(Ptr4 W, Ptr4 As, Ptr4 Ad,
                           float* __restrict__ wsrcA, float* __restrict__ wdstA) {
    const int dins[4]  = {9, 128, 256, 512};
    const int douts[4] = {128, 256, 512, 1534};
    int l = blockIdx.y, k = blockIdx.x;
    if (k >= dins[l]) return;
    const float* Wp = (l == 0) ? W.p0 : (l == 1) ? W.p1 : (l == 2) ? W.p2 : W.p3;
    const float* as = (l == 0) ? As.p0 : (l == 1) ? As.p1 : (l == 2) ? As.p2 : As.p3;
    const float* ad = (l == 0) ? Ad.p0 : (l == 1) ? Ad.p1 : (l == 2) ? Ad.p2 : Ad.p3;
    int NC = douts[l];
    const float* row = Wp + (size_t)k * NC;
    float ss = 0.f, sd = 0.f;
    for (int n = threadIdx.x; n < NC; n += 256) {
        float w = row[n];
        ss += w * as[n];
        sd += w * ad[n];
    }
    __shared__ float ls[8];
    int lane = threadIdx.x & 63, w4 = threadIdx.x >> 6;
    #pragma unroll
    for (int off = 32; off; off >>= 1) {
        ss += __shfl_down(ss, off, 64);
        sd += __shfl_down(sd, off, 64);
    }
    if (lane == 0) { ls[w4] = ss; ls[4 + w4] = sd; }
    __syncthreads();
    if (threadIdx.x == 0) {
        wsrcA[l * 512 + k] = ls[0] + ls[1] + ls[2] + ls[3];
        wdstA[l * 512 + k] = ls[4] + ls[5] + ls[6] + ls[7];
    }
}

// ---------------- all-layer W transpose + pad + f16 ----------------

__global__ void k_wbt_all(Ptr4 W, u16* __restrict__ WbTall) {
    const int Ks[3] = {128, 256, 512};
    const int NCs[3] = {256, 512, 1534};
    const int Nps[3] = {256, 512, 1536};
    const size_t offs[3] = {0, 256 * 128, 256 * 128 + 512 * 256};
    int l = blockIdx.z;
    int K = Ks[l], NC = NCs[l], Np = Nps[l];
    int n0 = blockIdx.x * 32, k0 = blockIdx.y * 32;
    if (n0 >= Np || k0 >= K) return;
    const float* Wp = (l == 0) ? W.p1 : (l == 1) ? W.p2 : W.p3;
    u16* WbT = WbTall + offs[l];
    __shared__ u16 tile[32][33];
    int tx = threadIdx.x & 31, ty = threadIdx.x >> 5;   // ty 0..7
    #pragma unroll
    for (int i = 0; i < 4; i++) {
        int k = k0 + ty + i * 8, n = n0 + tx;
        float v = (k < K && n < NC) ? Wp[(size_t)k * NC + n] : 0.f;
        tile[ty + i * 8][tx] = f2h(v);
    }
    __syncthreads();
    #pragma unroll
    for (int i = 0; i < 4; i++) {
        int n = n0 + ty + i * 8, k = k0 + tx;
        if (n < Np && k < K) WbT[(size_t)n * K + k] = tile[tx][ty + i * 8];
    }
}

// ---------------- scores ----------------

__global__ void k_scores0(const float* __restrict__ x, const float* __restrict__ wsrc,
                          const float* __restrict__ wdst, float* __restrict__ s_src,
                          float* __restrict__ s_dst) {
    int v = blockIdx.x * 256 + threadIdx.x;
    if (v >= NN) return;
    const float* r = x + (size_t)v * 9;
    float ss = 0.f, sd = 0.f;
    #pragma unroll
    for (int k = 0; k < 9; k++) { ss += r[k] * wsrc[k]; sd += r[k] * wdst[k]; }
    s_src[v] = ss; s_dst[v] = sd;
}

__global__ void k_scores_h(const u16* __restrict__ h, const float* __restrict__ wsrc,
                           const float* __restrict__ wdst, float* __restrict__ s_src,
                           float* __restrict__ s_dst, int din) {
    int v = blockIdx.x * 4 + (threadIdx.x >> 6);
    int lane = threadIdx.x & 63;
    if (v >= NN) return;
    const u16* row = h + (size_t)v * din;
    float ss = 0.f, sd = 0.f;
    for (int d = lane * 2; d < din; d += 128) {
        u32 u = *(const u32*)(row + d);
        float h0 = h2f((u16)(u & 0xffffu)), h1 = h2f((u16)(u >> 16));
        ss += h0 * wsrc[d] + h1 * wsrc[d + 1];
        sd += h0 * wdst[d] + h1 * wdst[d + 1];
    }
    #pragma unroll
    for (int off = 32; off; off >>= 1) {
        ss += __shfl_down(ss, off, 64);
        sd += __shfl_down(sd, off, 64);
    }
    if (lane == 0) { s_src[v] = ss; s_dst[v] = sd; }
}

// ---------------- fused softmax + aggregation ----------------

template <int TPN, int CPT>
__global__ __launch_bounds__(256) void k_agg_fused(const u16* __restrict__ h,
                                                   const int* __restrict__ row_ptr,
                                                   const int* __restrict__ col,
                                                   const float* __restrict__ s_src,
                                                   const float* __restrict__ s_dst,
                                                   u16* __restrict__ agg, int din) {
    constexpr int NPB = 256 / TPN;
    __shared__ float sm[NPB * 2];
    int grp = threadIdx.x / TPN;
    int lane = threadIdx.x % TPN;
    int v = blockIdx.x * NPB + grp;
    bool valid = v < NN;
    int st = 0, en = 0;
    float sd = 0.f;
    if (valid) { st = row_ptr[v]; en = row_ptr[v + 1]; sd = s_dst[v]; }

    float mx = -INFINITY;
    if (valid && lane < 64) {
        for (int p = st + lane; p < en; p += 64)
            mx = fmaxf(mx, lrelu_att(s_src[col[p]] + sd));
    }
    #pragma unroll
    for (int off = 32; off; off >>= 1) mx = fmaxf(mx, __shfl_xor(mx, off, 64));
    float sum = 0.f;
    if (valid && lane < 64) {
        for (int p = st + lane; p < en; p += 64)
            sum += __expf(lrelu_att(s_src[col[p]] + sd) - mx);
    }
    #pragma unroll
    for (int off = 32; off; off >>= 1) sum += __shfl_xor(sum, off, 64);
    if (lane == 0) { sm[grp * 2] = mx; sm[grp * 2 + 1] = 1.0f / (sum + 1e-16f); }
    __syncthreads();
    if (!valid) return;
    float m = sm[grp * 2], inv = sm[grp * 2 + 1];

    int d0 = lane * 2 * CPT;
    float acc[2 * CPT];
    #pragma unroll
    for (int i = 0; i < 2 * CPT; i++) acc[i] = 0.f;
    const u16* hb = h + d0;
    int p = st;
    for (; p + 2 <= en; p += 2) {
        int c0 = col[p], c1 = col[p + 1];
        float a0 = __expf(lrelu_att(s_src[c0] + sd) - m);
        float a1 = __expf(lrelu_att(s_src[c1] + sd) - m);
        u32 u0[CPT], u1[CPT];
        if constexpr (CPT == 1) {
            u0[0] = *(const u32*)(hb + (size_t)c0 * din);
            u1[0] = *(const u32*)(hb + (size_t)c1 * din);
        } else {
            uint2 t0 = *(const uint2*)(hb + (size_t)c0 * din);
            uint2 t1 = *(const uint2*)(hb + (size_t)c1 * din);
            u0[0] = t0.x; u0[1] = t0.y; u1[0] = t1.x; u1[1] = t1.y;
        }
        #pragma unroll
        for (int wv = 0; wv < CPT; wv++) {
            acc[2 * wv]     += a0 * h2f((u16)(u0[wv] & 0xffffu)) + a1 * h2f((u16)(u1[wv] & 0xffffu));
            acc[2 * wv + 1] += a0 * h2f((u16)(u0[wv] >> 16))     + a1 * h2f((u16)(u1[wv] >> 16));
        }
    }
    if (p < en) {
        int c0 = col[p];
        float a0 = __expf(lrelu_att(s_src[c0] + sd) - m);
        u32 u0[CPT];
        if constexpr (CPT == 1) {
            u0[0] = *(const u32*)(hb + (size_t)c0 * din);
        } else {
            uint2 t0 = *(const uint2*)(hb + (size_t)c0 * din);
            u0[0] = t0.x; u0[1] = t0.y;
        }
        #pragma unroll
        for (int wv = 0; wv < CPT; wv++) {
            acc[2 * wv]     += a0 * h2f((u16)(u0[wv] & 0xffffu));
            acc[2 * wv + 1] += a0 * h2f((u16)(u0[wv] >> 16));
        }
    }
    u32 o[CPT];
    #pragma unroll
    for (int wv = 0; wv < CPT; wv++)
        o[wv] = (u32)f2h(acc[2 * wv] * inv) | ((u32)f2h(acc[2 * wv + 1] * inv) << 16);
    if constexpr (CPT == 1) {
        *(u32*)(agg + (size_t)v * din + d0) = o[0];
    } else {
        uint2 ov; ov.x = o[0]; ov.y = o[1];
        *(uint2*)(agg + (size_t)v * din + d0) = ov;
    }
}

// layer-0 variant: din=9, f32 input; one wave per node, lanes 0..8 gather.
__global__ __launch_bounds__(256) void k_agg0_fused(const float* __restrict__ x,
                                                    const int* __restrict__ row_ptr,
                                                    const int* __restrict__ col,
                                                    const float* __restrict__ s_src,
                                                    const float* __restrict__ s_dst,
                                                    float* __restrict__ agg0) {
    __shared__ float sm[4 * 2];
    int grp = threadIdx.x >> 6;
    int lane = threadIdx.x & 63;
    int v = blockIdx.x * 4 + grp;
    bool valid = v < NN;
    int st = 0, en = 0;
    float sd = 0.f;
    if (valid) { st = row_ptr[v]; en = row_ptr[v + 1]; sd = s_dst[v]; }
    float mx = -INFINITY;
    if (valid) {
        for (int p = st + lane; p < en; p += 64)
            mx = fmaxf(mx, lrelu_att(s_src[col[p]] + sd));
    }
    #pragma unroll
    for (int off = 32; off; off >>= 1) mx = fmaxf(mx, __shfl_xor(mx, off, 64));
    float sum = 0.f;
    if (valid) {
        for (int p = st + lane; p < en; p += 64)
            sum += __expf(lrelu_att(s_src[col[p]] + sd) - mx);
    }
    #pragma unroll
    for (int off = 32; off; off >>= 1) sum += __shfl_xor(sum, off, 64);
    if (lane == 0) { sm[grp * 2] = mx; sm[grp * 2 + 1] = 1.0f / (sum + 1e-16f); }
    __syncthreads();
    if (!valid || lane >= 9) return;
    float m = sm[grp * 2], inv = sm[grp * 2 + 1];
    float acc = 0.f;
    for (int p = st; p < en; p++) {
        int c = col[p];
        float a = __expf(lrelu_att(s_src[c] + sd) - m);
        acc += a * x[(size_t)c * 9 + lane];
    }
    agg0[(size_t)v * 9 + lane] = acc * inv;
}

// ---------------- layer 0 GEMM: agg0[NN][9] f32 @ W0[9][128] + bias + lrelu ----------------

__global__ __launch_bounds__(256) void k_gemm0(const float* __restrict__ agg0,
                                               const float* __restrict__ W,
                                               const float* __restrict__ bias,
                                               u16* __restrict__ out) {
    __shared__ float Ws[9 * 128];
    for (int i = threadIdx.x; i < 9 * 128; i += 256) Ws[i] = W[i];
    __syncthreads();
    int node = blockIdx.x * 2 + (threadIdx.x >> 7);
    int n = threadIdx.x & 127;
    if (node >= NN) return;
    const float* xr = agg0 + (size_t)node * 9;
    float acc = bias[n];
    #pragma unroll
    for (int k = 0; k < 9; k++) acc += xr[k] * Ws[k * 128 + n];
    acc = (acc > 0.f) ? acc : NEG_ACT * acc;
    out[(size_t)node * 128 + n] = f2h(acc);
}

// ---------------- 128x128 MFMA GEMM (kept for layer 1) ----------------

#define BM 128
#define BK 32

__global__ __launch_bounds__(256) void k_gemm_f16(const u16* __restrict__ A,
                                                  const u16* __restrict__ B,
                                                  const float* __restrict__ bias,
                                                  u16* __restrict__ C,
                                                  int K, int ldC, int NC, int ntx) {
    int nwg = gridDim.x;
    int b = blockIdx.x;
    int q = nwg >> 3, r = nwg & 7;
    int xcd = b & 7, idx = b >> 3;
    int wg = (xcd < r ? xcd * (q + 1) : r * (q + 1) + (xcd - r) * q) + idx;
    int row0 = (wg / ntx) * BM;
    int col0 = (wg % ntx) * BM;

    __shared__ u16 lds[2][2][BM * BK];   // 32 KiB
    int tid = threadIdx.x;
    int lane = tid & 63, w = tid >> 6;
    int wr = w >> 1, wc = w & 1;

    f32x4 acc[4][4];
    #pragma unroll
    for (int m = 0; m < 4; m++)
        #pragma unroll
        for (int n = 0; n < 4; n++)
            #pragma unroll
            for (int rr2 = 0; rr2 < 4; rr2++) acc[m][n][rr2] = 0.f;

    int nt = K / BK;

    auto stage = [&](int buf, int t) {
        int k0 = t * BK;
        #pragma unroll
        for (int c = 0; c < 2; c++) {
            int idx2 = tid + c * 256;           // 0..511
            int rr2 = idx2 >> 2, kc = idx2 & 3;
            int kcs = kc ^ (rr2 & 3);           // pre-swizzled global source
            gl_lds16(A + (size_t)(row0 + rr2) * K + k0 + kcs * 8, &lds[buf][0][idx2 * 8]);
            gl_lds16(B + (size_t)(col0 + rr2) * K + k0 + kcs * 8, &lds[buf][1][idx2 * 8]);
        }
    };

    auto compute = [&](int buf) {
        const u16* As = &lds[buf][0][0];
        const u16* Bs = &lds[buf][1][0];
        int kg = lane >> 4, rl = lane & 15;
        half8 af[4], bfr[4];
        #pragma unroll
        for (int m = 0; m < 4; m++) {
            int rr2 = wr * 64 + m * 16 + rl;
            af[m] = *(const half8*)(As + rr2 * BK + (kg ^ (rr2 & 3)) * 8);
        }
        #pragma unroll
        for (int n = 0; n < 4; n++) {
            int rr2 = wc * 64 + n * 16 + rl;
            bfr[n] = *(const half8*)(Bs + rr2 * BK + (kg ^ (rr2 & 3)) * 8);
        }
        #pragma unroll
        for (int m = 0; m < 4; m++)
            #pragma unroll
            for (int n = 0; n < 4; n++)
                acc[m][n] = __builtin_amdgcn_mfma_f32_16x16x32_f16(af[m], bfr[n], acc[m][n], 0, 0, 0);
    };

    stage(0, 0);
    __syncthreads();
    for (int t = 0; t < nt; t++) {
        if (t + 1 < nt) stage((t + 1) & 1, t + 1);
        compute(t & 1);
        __syncthreads();
    }

    u16* ep = ((u16*)lds) + w * (32 * 72);
    int kg = lane >> 4, rl = lane & 15;
    int rrow = lane >> 3;
    int c8 = (lane & 7) * 8;
    #pragma unroll
    for (int half = 0; half < 2; half++) {
        #pragma unroll
        for (int m2 = 0; m2 < 2; m2++) {
            int m = half * 2 + m2;
            #pragma unroll
            for (int n = 0; n < 4; n++) {
                int colg = col0 + wc * 64 + n * 16 + rl;
                float bb = (colg < NC) ? bias[colg] : 0.f;
                #pragma unroll
                for (int rr2 = 0; rr2 < 4; rr2++) {
                    float o = acc[m][n][rr2] + bb;
                    o = (o > 0.f) ? o : NEG_ACT * o;
                    ep[(m2 * 16 + kg * 4 + rr2) * 72 + n * 16 + rl] = f2h(o);
                }
            }
        }
        #pragma unroll
        for (int it = 0; it < 4; it++) {
            int rloc = it * 8 + rrow;
            half8 vv = *(const half8*)(ep + rloc * 72 + c8);
            int rowg = row0 + wr * 64 + half * 32 + rloc;
            *(half8*)(C + (size_t)rowg * ldC + col0 + wc * 64 + c8) = vv;
        }
    }
}

// ---------------- 256x256 BK=64 8-phase MFMA GEMM (layers 2,3) ----------------
// T2+T3+T4+T5 template (guide §5): 512 thr / 8 waves (2x4), per-wave 128x64 out,
// 128 KiB LDS double-buffered, half-tiles split along K ([kslice][256 rows][32 el]
// => 64 B rows: kg-slot reads are inherently bank-balanced, no XOR swizzle needed),
// counted vmcnt(4) only at phase 1/3 (never 0 in-loop), setprio around MFMA.

__global__ __launch_bounds__(512, 2) void k_gemm256(const u16* __restrict__ A,
                                                    const u16* __restrict__ B,
                                                    const float* __restrict__ bias,
                                                    u16* __restrict__ C,
                                                    int K, int ldC, int NC, int ntx, int M) {
    __shared__ u16 sA[2][2][8192];   // [buf][kslice][row*32 + k]  64 KiB
    __shared__ u16 sB[2][2][8192];   // 64 KiB

    int nwg = gridDim.x, b = blockIdx.x;
    int q = nwg >> 3, r = nwg & 7;
    int xcd = b & 7, bidx = b >> 3;
    int wg = (xcd < r ? xcd * (q + 1) : r * (q + 1) + (xcd - r) * q) + bidx;
    int row0 = (wg / ntx) * 256;
    int col0 = (wg % ntx) * 256;

    int tid = threadIdx.x;
    int w = tid >> 6, lane = tid & 63;
    int wm = w >> 2, wn = w & 3;           // 2 x 4 wave grid
    int rl = lane & 15, kg = lane >> 4;

    f32x4 acc[8][4];
    #pragma unroll
    for (int m = 0; m < 8; m++)
        #pragma unroll
        for (int n = 0; n < 4; n++)
            #pragma unroll
            for (int i = 0; i < 4; i++) acc[m][n][i] = 0.f;

    // stage one half-tile (kslice h of K-tile t) into buf: 2 gl_lds / thread.
    // LDS dest is linear in lane (wave-uniform base + lane*16B); global source
    // row-clamped for the ragged last M tile.
    auto stageA = [&](int h, int t, int buf) {
        #pragma unroll
        for (int i = 0; i < 2; i++) {
            int idx = i * 512 + tid;            // 0..1023
            int rr = idx >> 2, s = idx & 3;
            int ra = row0 + rr; ra = (ra < M) ? ra : (M - 1);
            gl_lds16(A + (size_t)ra * K + t * 64 + h * 32 + s * 8, &sA[buf][h][idx * 8]);
        }
    };
    auto stageB = [&](int h, int t, int buf) {
        #pragma unroll
        for (int i = 0; i < 2; i++) {
            int idx = i * 512 + tid;
            int rr = idx >> 2, s = idx & 3;
            gl_lds16(B + (size_t)(col0 + rr) * K + t * 64 + h * 32 + s * 8, &sB[buf][h][idx * 8]);
        }
    };

    half8 af[8], bf0, bf1;
    auto ldA8 = [&](int buf, int h) {
        #pragma unroll
        for (int mf = 0; mf < 8; mf++)
            af[mf] = *(const half8*)&sA[buf][h][(wm * 128 + mf * 16 + rl) * 32 + kg * 8];
    };
    auto ldB2 = [&](int buf, int h, int n0) {
        bf0 = *(const half8*)&sB[buf][h][(wn * 64 + n0 * 16 + rl) * 32 + kg * 8];
        bf1 = *(const half8*)&sB[buf][h][(wn * 64 + (n0 + 1) * 16 + rl) * 32 + kg * 8];
    };
    auto mm16 = [&](int n0) {
        __builtin_amdgcn_s_setprio(1);
        #pragma unroll
        for (int mf = 0; mf < 8; mf++) {
            acc[mf][n0]     = __builtin_amdgcn_mfma_f32_16x16x32_f16(af[mf], bf0, acc[mf][n0], 0, 0, 0);
            acc[mf][n0 + 1] = __builtin_amdgcn_mfma_f32_16x16x32_f16(af[mf], bf1, acc[mf][n0 + 1], 0, 0, 0);
        }
        __builtin_amdgcn_s_setprio(0);
    };

    #define SBAR() do { __builtin_amdgcn_sched_barrier(0); \
                        __builtin_amdgcn_s_barrier(); \
                        __builtin_amdgcn_sched_barrier(0); } while (0)

    int nt = K >> 6;    // K-tiles of 64; requires nt >= 2

    // prologue: fully stage K-tile 0; wait first two half-tiles (A-h0, B-h0)
    stageA(0, 0, 0); stageB(0, 0, 0); stageA(1, 0, 0); stageB(1, 0, 0);
    asm volatile("s_waitcnt vmcnt(4)" ::: "memory");
    SBAR();

    for (int t = 0; t < nt; t++) {
        int rb = t & 1, wb = rb ^ 1;
        bool pf = (t + 1 < nt);
        // phase 0: kslice 0, n-frags 0-1; prefetch A-h0(t+1)
        ldA8(rb, 0); ldB2(rb, 0, 0);
        if (pf) stageA(0, t + 1, wb);
        mm16(0);
        SBAR();
        // phase 1: kslice 0, n-frags 2-3; prefetch B-h0(t+1); retire A-h1(t),B-h1(t)
        ldB2(rb, 0, 2);
        if (pf) stageB(0, t + 1, wb);
        mm16(2);
        __builtin_amdgcn_sched_barrier(0);
        if (pf) asm volatile("s_waitcnt vmcnt(4)" ::: "memory");
        else    asm volatile("s_waitcnt vmcnt(0)" ::: "memory");
        SBAR();
        // phase 2: kslice 1, n-frags 0-1; prefetch A-h1(t+1)
        ldA8(rb, 1); ldB2(rb, 1, 0);
        if (pf) stageA(1, t + 1, wb);
        mm16(0);
        SBAR();
        // phase 3: kslice 1, n-frags 2-3; prefetch B-h1(t+1); retire A-h0(t+1),B-h0(t+1)
        ldB2(rb, 1, 2);
        if (pf) stageB(1, t + 1, wb);
        mm16(2);
        __builtin_amdgcn_sched_barrier(0);
        if (pf) asm volatile("s_waitcnt vmcnt(4)" ::: "memory");
        SBAR();
    }
    #undef SBAR

    // epilogue: per-wave 32x72 LDS staging, coalesced half8 stores
    u16* ep = ((u16*)sA) + w * (32 * 72);
    float bv[4];
    #pragma unroll
    for (int n = 0; n < 4; n++) {
        int colg = col0 + wn * 64 + n * 16 + rl;
        bv[n] = (colg < NC) ? bias[colg] : 0.f;
    }
    int rrow = lane >> 3, c8 = (lane & 7) * 8;
    #pragma unroll
    for (int mf2 = 0; mf2 < 4; mf2++) {
        #pragma unroll
        for (int sub = 0; sub < 2; sub++) {
            int mf = mf2 * 2 + sub;
            #pragma unroll
            for (int n = 0; n < 4; n++) {
                #pragma unroll
                for (int rg = 0; rg < 4; rg++) {
                    float o = acc[mf][n][rg] + bv[n];
                    o = (o > 0.f) ? o : NEG_ACT * o;
                    ep[(sub * 16 + kg * 4 + rg) * 72 + n * 16 + rl] = f2h(o);
                }
            }
        }
        #pragma unroll
        for (int it = 0; it < 4; it++) {
            int rloc = it * 8 + rrow;
            half8 vv = *(const half8*)(ep + rloc * 72 + c8);
            int rowg = row0 + wm * 128 + mf2 * 32 + rloc;
            if (rowg < M)
                *(half8*)(C + (size_t)rowg * ldC + col0 + wn * 64 + c8) = vv;
        }
    }
}

// ---------------- GraphNorm: stats then apply (apply optionally fuses pooling) ----------------

__global__ void k_gn_stats(const u16* __restrict__ h, const int* __restrict__ batch,
                           float* __restrict__ gsum, float* __restrict__ gsq,
                           int dout, int ld) {
    int d0 = (blockIdx.x * 256 + threadIdx.x) * 2;
    if (d0 >= dout) return;
    int r0 = blockIdx.y * 64;
    float s0 = 0.f, s1 = 0.f, q0 = 0.f, q1 = 0.f;
    int gcur = batch[r0];
    for (int rr = 0; rr < 64; rr++) {
        int r = r0 + rr;
        if (r >= NN) break;
        int g = batch[r];
        if (g != gcur) {
            atomicAdd(&gsum[(size_t)gcur * ld + d0], s0);
            atomicAdd(&gsum[(size_t)gcur * ld + d0 + 1], s1);
            atomicAdd(&gsq[(size_t)gcur * ld + d0], q0);
            atomicAdd(&gsq[(size_t)gcur * ld + d0 + 1], q1);
            s0 = s1 = q0 = q1 = 0.f; gcur = g;
        }
        u32 u = *(const u32*)(h + (size_t)r * ld + d0);
        float v0 = h2f((u16)(u & 0xffffu)), v1 = h2f((u16)(u >> 16));
        s0 += v0; s1 += v1; q0 += v0 * v0; q1 += v1 * v1;
    }
    atomicAdd(&gsum[(size_t)gcur * ld + d0], s0);
    atomicAdd(&gsum[(size_t)gcur * ld + d0 + 1], s1);
    atomicAdd(&gsq[(size_t)gcur * ld + d0], q0);
    atomicAdd(&gsq[(size_t)gcur * ld + d0 + 1], q1);
}

template <int DOPOOL>
__global__ void k_gn_apply(const u16* __restrict__ h, const int* __restrict__ batch,
                           const float* __restrict__ gsum, const float* __restrict__ gsq,
                           const int* __restrict__ counts, const float* __restrict__ ms,
                           const float* __restrict__ gam, const float* __restrict__ bet,
                           u16* __restrict__ out, float* __restrict__ psum,
                           u32* __restrict__ pmax, int dout, int ld) {
    int d0 = (blockIdx.x * 256 + threadIdx.x) * 2;
    if (d0 >= dout) return;
    int r0 = blockIdx.y * 64;
    float ms0 = ms[d0], ms1 = ms[d0 + 1];
    float g0 = gam[d0], g1 = gam[d0 + 1];
    float b0 = bet[d0], b1 = bet[d0 + 1];
    int gcur = -1;
    float sub0 = 0.f, sub1 = 0.f, sc0 = 0.f, sc1 = 0.f;
    float p0 = 0.f, p1 = 0.f, m0 = -INFINITY, m1 = -INFINITY;
    for (int rr = 0; rr < 64; rr++) {
        int r = r0 + rr;
        if (r >= NN) break;
        int g = batch[r];
        if (g != gcur) {
            if (DOPOOL && gcur >= 0) {
                atomicAdd(&psum[(size_t)gcur * 1536 + d0], p0);
                atomicAdd(&psum[(size_t)gcur * 1536 + d0 + 1], p1);
                atomicMax(&pmax[(size_t)gcur * 1536 + d0], enc_f(m0));
                atomicMax(&pmax[(size_t)gcur * 1536 + d0 + 1], enc_f(m1));
                p0 = p1 = 0.f; m0 = m1 = -INFINITY;
            }
            gcur = g;
            float inv = 1.0f / (float)counts[g];
            float mm0 = gsum[(size_t)g * ld + d0] * inv;
            float mm1 = gsum[(size_t)g * ld + d0 + 1] * inv;
            float q0 = gsq[(size_t)g * ld + d0] * inv;
            float q1 = gsq[(size_t)g * ld + d0 + 1] * inv;
            float v0 = fmaxf(q0 - (2.f * ms0 - ms0 * ms0) * mm0 * mm0, 0.f);
            float v1 = fmaxf(q1 - (2.f * ms1 - ms1 * ms1) * mm1 * mm1, 0.f);
            sub0 = ms0 * mm0; sub1 = ms1 * mm1;
            sc0 = g0 * rsqrtf(v0 + EPS_GN);
            sc1 = g1 * rsqrtf(v1 + EPS_GN);
        }
        u32 u = *(const u32*)(h + (size_t)r * ld + d0);
        float o0 = (h2f((u16)(u & 0xffffu)) - sub0) * sc0 + b0;
        float o1 = (h2f((u16)(u >> 16)) - sub1) * sc1 + b1;
        if (DOPOOL) {
            p0 += o0; p1 += o1;
            m0 = fmaxf(m0, o0); m1 = fmaxf(m1, o1);
        } else {
            u32 wv = (u32)f2h(o0) | ((u32)f2h(o1) << 16);
            *(u32*)(out + (size_t)r * dout + d0) = wv;
        }
    }
    if (DOPOOL && gcur >= 0) {
        atomicAdd(&psum[(size_t)gcur * 1536 + d0], p0);
        atomicAdd(&psum[(size_t)gcur * 1536 + d0 + 1], p1);
        atomicMax(&pmax[(size_t)gcur * 1536 + d0], enc_f(m0));
        atomicMax(&pmax[(size_t)gcur * 1536 + d0 + 1], enc_f(m1));
    }
}

__global__ void k_pool2(const float* __restrict__ psum, const u32* __restrict__ pmax,
                        const int* __restrict__ counts, float* __restrict__ out,
                        int dout, int ld) {
    int d = blockIdx.x * 256 + threadIdx.x;
    if (d >= dout) return;
    int g = blockIdx.y;
    float inv = 1.0f / (float)counts[g];
    out[(size_t)g * 2 * dout + d] = psum[(size_t)g * ld + d] * inv;
    out[(size_t)g * 2 * dout + dout + d] = dec_f(pmax[(size_t)g * ld + d]);
}

// ---------------- launch ----------------

extern "C" void kernel_launch(void* const* d_in, const int* in_sizes, int n_in,
                              void* d_out, int out_size, void* d_ws, size_t ws_size,
                              hipStream_t stream) {
    const float* x = (const float*)d_in[0];
    const int* ei = (const int*)d_in[1];
    const int* batch = (const int*)d_in[2];
    const float *Wl[4], *Asr[4], *Ads[4], *Bi[4], *Ga[4], *Be[4], *Ms[4];
    for (int l = 0; l < 4; l++) {
        int b = 3 + 7 * l;
        Wl[l]  = (const float*)d_in[b];
        Asr[l] = (const float*)d_in[b + 1];
        Ads[l] = (const float*)d_in[b + 2];
        Bi[l]  = (const float*)d_in[b + 3];
        Ga[l]  = (const float*)d_in[b + 4];
        Be[l]  = (const float*)d_in[b + 5];
        Ms[l]  = (const float*)d_in[b + 6];
    }

    char* ws = (char*)d_ws;
    size_t off = 0;
    auto alloc = [&](size_t bytes) -> char* {
        char* p = ws + off;
        off += (bytes + 255) & ~(size_t)255;
        return p;
    };
    u16*   actA   = (u16*)alloc((size_t)MPAD * 512 * 2);    // normalized h (layers 0-2)
    u16*   actB   = (u16*)alloc((size_t)MPAD * 1536 * 2);   // GEMM output
    u16*   agg    = (u16*)alloc((size_t)MPAD * 512 * 2);    // aggregated pre-projection (f16)
    float* agg0   = (float*)alloc((size_t)NN * 9 * 4);      // layer-0 aggregated (f32)
    u16*   WbTall = (u16*)alloc((size_t)(256 * 128 + 512 * 256 + 1536 * 512) * 2);
    float* wsrcA  = (float*)alloc((size_t)4 * 512 * 4);
    float* wdstA  = (float*)alloc((size_t)4 * 512 * 4);
    float* s_src  = (float*)alloc((size_t)NN * 4);
    float* s_dst  = (float*)alloc((size_t)NN * 4);
    int* row_ptr  = (int*)alloc((size_t)(NN + 1) * 4);
    int* cursor   = (int*)alloc((size_t)NN * 4);
    int* colA     = (int*)alloc((size_t)ET * 4);
    int* counts   = (int*)alloc((size_t)NG * 4);
    int* bsum     = (int*)alloc((size_t)NBLK * 4);
    int* boff     = (int*)alloc((size_t)NBLK * 4);

    // --- contiguous zero region (one memset) ---
    char* zbase = ws + off;
    int* deg      = (int*)alloc((size_t)NN * 4);
    float* gsumA  = (float*)alloc((size_t)4 * NG * 1536 * 4);
    float* gsqA   = (float*)alloc((size_t)4 * NG * 1536 * 4);
    float* psum   = (float*)alloc((size_t)NG * 1536 * 4);
    u32*   pmax   = (u32*)alloc((size_t)NG * 1536 * 4);
    size_t zbytes = (size_t)((ws + off) - zbase);
    hipMemsetAsync(zbase, 0, zbytes, stream);

    k_bounds<<<1, 64, 0, stream>>>(batch, counts);
    k_deg<<<(ET + 255) / 256, 256, 0, stream>>>(ei, deg);
    k_scan1<<<NBLK, 256, 0, stream>>>(deg, bsum);
    k_scan2<<<1, 256, 0, stream>>>(bsum, boff, row_ptr + NN);
    k_scan3<<<NBLK, 256, 0, stream>>>(deg, boff, row_ptr, cursor);
    k_scatter<<<(ET + 255) / 256, 256, 0, stream>>>(ei, cursor, colA);

    Ptr4 Wp{Wl[0], Wl[1], Wl[2], Wl[3]};
    Ptr4 Ap{Asr[0], Asr[1], Asr[2], Asr[3]};
    Ptr4 Dp{Ads[0], Ads[1], Ads[2], Ads[3]};
    k_wvec_all<<<dim3(512, 4), 256, 0, stream>>>(Wp, Ap, Dp, wsrcA, wdstA);
    k_wbt_all<<<dim3(48, 16, 3), 256, 0, stream>>>(Wp, WbTall);

    const int dims[5] = {9, 128, 256, 512, 1534};
    const size_t wbtOffs[3] = {0, 256 * 128, 256 * 128 + 512 * 256};
    const int RY = (NN + 63) / 64;   // 313 row chunks
    const int RT256 = (MPAD + 255) / 256;   // 79 row tiles for the 256 GEMM

    for (int l = 0; l < 4; l++) {
        int din = dims[l], dout = dims[l + 1];
        int ldo = (dout == 1534) ? 1536 : dout;
        float* gsum = gsumA + (size_t)l * NG * 1536;
        float* gsq  = gsqA  + (size_t)l * NG * 1536;
        const float* wsrc = wsrcA + l * 512;
        const float* wdst = wdstA + l * 512;

        if (l == 0) {
            k_scores0<<<(NN + 255) / 256, 256, 0, stream>>>(x, wsrc, wdst, s_src, s_dst);
            k_agg0_fused<<<(NN + 3) / 4, 256, 0, stream>>>(x, row_ptr, colA, s_src, s_dst, agg0);
            k_gemm0<<<(NN + 1) / 2, 256, 0, stream>>>(agg0, Wl[0], Bi[0], actB);
        } else if (l == 1) {
            k_scores_h<<<(NN + 3) / 4, 256, 0, stream>>>(actA, wsrc, wdst, s_src, s_dst, din);
            k_agg_fused<64, 1><<<(NN + 3) / 4, 256, 0, stream>>>(actA, row_ptr, colA, s_src, s_dst, agg, din);
            int ntx = ldo / 128;
            int nwg = ntx * (MPAD / 128);
            k_gemm_f16<<<nwg, 256, 0, stream>>>(agg, WbTall + wbtOffs[0], Bi[1], actB,
                                                din, ldo, dout, ntx);
        } else {
            k_scores_h<<<(NN + 3) / 4, 256, 0, stream>>>(actA, wsrc, wdst, s_src, s_dst, din);
            if (din == 256)
                k_agg_fused<64, 2><<<(NN + 3) / 4, 256, 0, stream>>>(actA, row_ptr, colA, s_src, s_dst, agg, din);
            else
                k_agg_fused<128, 2><<<(NN + 1) / 2, 256, 0, stream>>>(actA, row_ptr, colA, s_src, s_dst, agg, din);
            int ntx = ldo / 256;            // 2 (l=2) or 6 (l=3)
            int nwg = ntx * RT256;          // 158 or 474
            k_gemm256<<<nwg, 512, 0, stream>>>(agg, WbTall + wbtOffs[l - 1], Bi[l], actB,
                                               din, ldo, dout, ntx, MPAD);
        }

        dim3 gs((dout / 2 + 255) / 256, RY);
        k_gn_stats<<<gs, 256, 0, stream>>>(actB, batch, gsum, gsq, dout, ldo);
        if (l < 3)
            k_gn_apply<0><<<gs, 256, 0, stream>>>(actB, batch, gsum, gsq, counts,
                                                  Ms[l], Ga[l], Be[l], actA, psum, pmax, dout, ldo);
        else
            k_gn_apply<1><<<gs, 256, 0, stream>>>(actB, batch, gsum, gsq, counts,
                                                  Ms[l], Ga[l], Be[l], actA, psum, pmax, dout, ldo);
    }

    dim3 gp2((1534 + 255) / 256, NG);
    k_pool2<<<gp2, 256, 0, stream>>>(psum, pmax, counts, (float*)d_out, 1534, 1536);
}